// Round 2
// baseline (417.570 us; speedup 1.0000x reference)
//
#include <hip/hip_runtime.h>

#define NN 10000
#define NE 320000
#define FDIM 128
#define NRBF 20
#define PHI_DIM 384

// ---------------- node MLP: phi = silu(S@W1+b1)@W2 + b2 ----------------
__global__ void phi_kernel(const float* __restrict__ S, const float* __restrict__ W1,
                           const float* __restrict__ b1, const float* __restrict__ W2,
                           const float* __restrict__ b2, float* __restrict__ phi) {
  __shared__ float s_s[8][FDIM];
  __shared__ float h_s[8][FDIM];
  const int t = threadIdx.x;
  const int n0 = blockIdx.x * 8;
#pragma unroll
  for (int n = 0; n < 8; n++) s_s[n][t] = S[(n0 + n) * FDIM + t];
  __syncthreads();
  float acc[8];
#pragma unroll
  for (int n = 0; n < 8; n++) acc[n] = 0.f;
  for (int k = 0; k < FDIM; k++) {
    float w = W1[k * FDIM + t];
#pragma unroll
    for (int n = 0; n < 8; n++) acc[n] += s_s[n][k] * w;
  }
  float bb = b1[t];
#pragma unroll
  for (int n = 0; n < 8; n++) {
    float x = acc[n] + bb;
    h_s[n][t] = x / (1.0f + expf(-x));
  }
  __syncthreads();
  float a0[8], a1[8], a2[8];
#pragma unroll
  for (int n = 0; n < 8; n++) { a0[n] = 0.f; a1[n] = 0.f; a2[n] = 0.f; }
  for (int k = 0; k < FDIM; k++) {
    float w0 = W2[k * PHI_DIM + t];
    float w1 = W2[k * PHI_DIM + t + 128];
    float w2 = W2[k * PHI_DIM + t + 256];
#pragma unroll
    for (int n = 0; n < 8; n++) {
      float hv = h_s[n][k];
      a0[n] += hv * w0;
      a1[n] += hv * w1;
      a2[n] += hv * w2;
    }
  }
  float c0 = b2[t], c1 = b2[t + 128], c2 = b2[t + 256];
#pragma unroll
  for (int n = 0; n < 8; n++) {
    float* p = phi + (size_t)(n0 + n) * PHI_DIM;
    p[t] = a0[n] + c0;
    p[t + 128] = a1[n] + c1;
    p[t + 256] = a2[n] + c2;
  }
}

// ---------------- CSR build ----------------
__global__ void count_kernel(const int* __restrict__ idx_i, int* __restrict__ counts) {
  int e = blockIdx.x * blockDim.x + threadIdx.x;
  if (e < NE) atomicAdd(&counts[idx_i[e]], 1);
}

__global__ void scan_kernel(const int* __restrict__ counts, int* __restrict__ offsets) {
  __shared__ int s[1024];
  const int t = threadIdx.x;
  const int CH = 10;  // 1024*10 >= 10000
  int base = t * CH;
  int sum = 0;
#pragma unroll
  for (int i = 0; i < CH; i++) {
    int idx = base + i;
    if (idx < NN) sum += counts[idx];
  }
  s[t] = sum;
  __syncthreads();
  for (int off = 1; off < 1024; off <<= 1) {
    int v = (t >= off) ? s[t - off] : 0;
    __syncthreads();
    s[t] += v;
    __syncthreads();
  }
  int run = s[t] - sum;  // exclusive prefix
  for (int i = 0; i < CH; i++) {
    int idx = base + i;
    if (idx < NN) {
      offsets[idx] = run;
      run += counts[idx];
    }
  }
  if (t == 1023) offsets[NN] = s[1023];
}

// store {edge, j} so the hot loop has one less dependent gather level
__global__ void fill_kernel(const int* __restrict__ idx_i, const int* __restrict__ idx_j,
                            const int* __restrict__ offsets, int* __restrict__ cursor,
                            int2* __restrict__ elist) {
  int e = blockIdx.x * blockDim.x + threadIdx.x;
  if (e < NE) {
    int i = idx_i[e];
    int pos = atomicAdd(&cursor[i], 1);
    elist[offsets[i] + pos] = make_int2(e, idx_j[e]);
  }
}

// ---------------- node-centric accumulation: 4 edge-groups x 128 features ----------------
__global__ void node_kernel(const int2* __restrict__ elist, const float* __restrict__ rel_dir,
                            const float* __restrict__ cut, const float* __restrict__ rbf,
                            const float* __restrict__ Wr, const float* __restrict__ br,
                            const float* __restrict__ phi, const float* __restrict__ sf,
                            const float* __restrict__ vf, const int* __restrict__ offsets,
                            float* __restrict__ out) {
  __shared__ float wr_s[NRBF * PHI_DIM];    // 30720 B
  __shared__ float red[4][4][FDIM];         // 8192 B : [group][ss,vx,vy,vz][feat]
  const int t = threadIdx.x;
  const int f = t & 127;
  const int g = t >> 7;  // 0..3
  for (int i = t; i < NRBF * PHI_DIM; i += 512) wr_s[i] = Wr[i];
  __syncthreads();
  const int n = blockIdx.x;
  const int beg = offsets[n], end = offsets[n + 1];
  const float br0 = br[f], br1 = br[f + 128], br2 = br[f + 256];
  float ss = 0.f, vx = 0.f, vy = 0.f, vz = 0.f;
  for (int p = beg + g; p < end; p += 4) {
    int2 ej = elist[p];
    const int e = ej.x, j = ej.y;
    float c = cut[e];
    float dx = rel_dir[e * 3 + 0], dy = rel_dir[e * 3 + 1], dz = rel_dir[e * 3 + 2];
    float rv[NRBF];
    const float4* rb4 = (const float4*)(rbf + (size_t)e * NRBF);  // 80B rows, 16B aligned
#pragma unroll
    for (int q = 0; q < 5; q++) {
      float4 v = rb4[q];
      rv[4 * q + 0] = v.x; rv[4 * q + 1] = v.y; rv[4 * q + 2] = v.z; rv[4 * q + 3] = v.w;
    }
    float g0 = br0, g1 = br1, g2 = br2;
#pragma unroll
    for (int r = 0; r < NRBF; r++) {
      float rvv = rv[r];
      g0 += rvv * wr_s[r * PHI_DIM + f];
      g1 += rvv * wr_s[r * PHI_DIM + f + 128];
      g2 += rvv * wr_s[r * PHI_DIM + f + 256];
    }
    g0 *= c; g1 *= c; g2 *= c;
    const float* pj = phi + (size_t)j * PHI_DIM;
    float vv = pj[f] * g0;
    float sv = pj[f + 128] * g1;
    float vs = pj[f + 256] * g2;
    ss += sv;
    const float* vfj = vf + (size_t)j * (FDIM * 3) + f * 3;
    vx += vfj[0] * vv + vs * dx;
    vy += vfj[1] * vv + vs * dy;
    vz += vfj[2] * vv + vs * dz;
  }
  red[g][0][f] = ss;
  red[g][1][f] = vx;
  red[g][2][f] = vy;
  red[g][3][f] = vz;
  __syncthreads();
  if (t < FDIM) {
    float s0 = red[0][0][f] + red[1][0][f] + red[2][0][f] + red[3][0][f];
    float x0 = red[0][1][f] + red[1][1][f] + red[2][1][f] + red[3][1][f];
    float y0 = red[0][2][f] + red[1][2][f] + red[2][2][f] + red[3][2][f];
    float z0 = red[0][3][f] + red[1][3][f] + red[2][3][f] + red[3][3][f];
    float inv = 1.0f / (float)(end - beg);
    out[(size_t)n * FDIM + f] = sf[(size_t)n * FDIM + f] + s0 * inv;
    float* ov = out + (size_t)NN * FDIM + (size_t)n * (FDIM * 3) + f * 3;
    const float* iv = vf + (size_t)n * (FDIM * 3) + f * 3;
    ov[0] = iv[0] + x0 * inv;
    ov[1] = iv[1] + y0 * inv;
    ov[2] = iv[2] + z0 * inv;
  }
}

extern "C" void kernel_launch(void* const* d_in, const int* in_sizes, int n_in,
                              void* d_out, int out_size, void* d_ws, size_t ws_size,
                              hipStream_t stream) {
  const int* idx_i = (const int*)d_in[0];
  const int* idx_j = (const int*)d_in[1];
  const float* rel_dir = (const float*)d_in[2];
  const float* cut = (const float*)d_in[3];
  const float* rbf = (const float*)d_in[4];
  const float* sf = (const float*)d_in[5];
  const float* vf = (const float*)d_in[6];
  const float* W1 = (const float*)d_in[7];
  const float* b1 = (const float*)d_in[8];
  const float* W2 = (const float*)d_in[9];
  const float* b2 = (const float*)d_in[10];
  const float* Wr = (const float*)d_in[11];
  const float* br = (const float*)d_in[12];
  float* out = (float*)d_out;

  char* w = (char*)d_ws;
  int* counts = (int*)w;                               // 10000 ints
  int* cursor = (int*)(w + 40000);                     // 10000 ints
  int* offsets = (int*)(w + 80000);                    // 10001 ints (pad to 10016)
  int2* elist = (int2*)(w + 80000 + 40064);            // 320000 int2 = 2.56 MB
  float* phi = (float*)(w + 80000 + 40064 + 2560000);  // 10000*384 floats

  hipMemsetAsync(w, 0, 80000, stream);  // zero counts + cursor
  hipLaunchKernelGGL(phi_kernel, dim3(NN / 8), dim3(128), 0, stream, sf, W1, b1, W2, b2, phi);
  hipLaunchKernelGGL(count_kernel, dim3((NE + 255) / 256), dim3(256), 0, stream, idx_i, counts);
  hipLaunchKernelGGL(scan_kernel, dim3(1), dim3(1024), 0, stream, counts, offsets);
  hipLaunchKernelGGL(fill_kernel, dim3((NE + 255) / 256), dim3(256), 0, stream, idx_i, idx_j,
                     offsets, cursor, elist);
  hipLaunchKernelGGL(node_kernel, dim3(NN), dim3(512), 0, stream, elist, rel_dir, cut, rbf, Wr,
                     br, phi, sf, vf, offsets, out);
}

// Round 3
// 295.279 us; speedup vs baseline: 1.4142x; 1.4142x over previous
//
#include <hip/hip_runtime.h>
#include <hip/hip_bf16.h>

#define NN 10000
#define NE 320000
#define FDIM 128
#define NRBF 20
#define PHI_DIM 384

typedef unsigned int uint;
typedef unsigned short ushort;

__device__ __forceinline__ ushort f2bf(float x) {
  __hip_bfloat16 b = __float2bfloat16(x);
  return *(ushort*)&b;
}
__device__ __forceinline__ float bf2f(ushort u) {
  return __uint_as_float(((uint)u) << 16);
}

// ---------------- node MLP: phi = silu(S@W1+b1)@W2 + b2 -> bf16 ----------------
__global__ void phi_kernel(const float* __restrict__ S, const float* __restrict__ W1,
                           const float* __restrict__ b1, const float* __restrict__ W2,
                           const float* __restrict__ b2, ushort* __restrict__ phi_b) {
  __shared__ float s_s[8][FDIM];
  __shared__ float h_s[8][FDIM];
  const int t = threadIdx.x;
  const int n0 = blockIdx.x * 8;
#pragma unroll
  for (int n = 0; n < 8; n++) s_s[n][t] = S[(n0 + n) * FDIM + t];
  __syncthreads();
  float acc[8];
#pragma unroll
  for (int n = 0; n < 8; n++) acc[n] = 0.f;
  for (int k = 0; k < FDIM; k++) {
    float w = W1[k * FDIM + t];
#pragma unroll
    for (int n = 0; n < 8; n++) acc[n] += s_s[n][k] * w;
  }
  float bb = b1[t];
#pragma unroll
  for (int n = 0; n < 8; n++) {
    float x = acc[n] + bb;
    h_s[n][t] = x / (1.0f + expf(-x));
  }
  __syncthreads();
  float a0[8], a1[8], a2[8];
#pragma unroll
  for (int n = 0; n < 8; n++) { a0[n] = 0.f; a1[n] = 0.f; a2[n] = 0.f; }
  for (int k = 0; k < FDIM; k++) {
    float w0 = W2[k * PHI_DIM + t];
    float w1 = W2[k * PHI_DIM + t + 128];
    float w2 = W2[k * PHI_DIM + t + 256];
#pragma unroll
    for (int n = 0; n < 8; n++) {
      float hv = h_s[n][k];
      a0[n] += hv * w0;
      a1[n] += hv * w1;
      a2[n] += hv * w2;
    }
  }
  float c0 = b2[t], c1 = b2[t + 128], c2 = b2[t + 256];
#pragma unroll
  for (int n = 0; n < 8; n++) {
    ushort* p = phi_b + (size_t)(n0 + n) * PHI_DIM;
    p[t] = f2bf(a0[n] + c0);
    p[t + 128] = f2bf(a1[n] + c1);
    p[t + 256] = f2bf(a2[n] + c2);
  }
}

// ---------------- vf -> bf16 planes [n][3][128] ----------------
__global__ void vfb_kernel(const float* __restrict__ vf, ushort* __restrict__ vfb) {
  const int n = blockIdx.x;
  const int t = threadIdx.x;
  const float* src = vf + (size_t)n * (FDIM * 3) + t * 3;
  ushort* dst = vfb + (size_t)n * (FDIM * 3);
  dst[t] = f2bf(src[0]);
  dst[t + 128] = f2bf(src[1]);
  dst[t + 256] = f2bf(src[2]);
}

// ---------------- CSR build ----------------
__global__ void count_kernel(const int* __restrict__ idx_i, int* __restrict__ counts) {
  int e = blockIdx.x * blockDim.x + threadIdx.x;
  if (e < NE) atomicAdd(&counts[idx_i[e]], 1);
}

__global__ void scan_kernel(const int* __restrict__ counts, int* __restrict__ offsets) {
  __shared__ int s[1024];
  const int t = threadIdx.x;
  const int CH = 10;  // 1024*10 >= 10000
  int base = t * CH;
  int sum = 0;
#pragma unroll
  for (int i = 0; i < CH; i++) {
    int idx = base + i;
    if (idx < NN) sum += counts[idx];
  }
  s[t] = sum;
  __syncthreads();
  for (int off = 1; off < 1024; off <<= 1) {
    int v = (t >= off) ? s[t - off] : 0;
    __syncthreads();
    s[t] += v;
    __syncthreads();
  }
  int run = s[t] - sum;  // exclusive prefix
  for (int i = 0; i < CH; i++) {
    int idx = base + i;
    if (idx < NN) {
      offsets[idx] = run;
      run += counts[idx];
    }
  }
  if (t == 1023) offsets[NN] = s[1023];
}

// stage CSR-ordered 64-B edge records: {j, cut, dx, dy, dz, pad, rbf[20] bf16}
__global__ void stage_kernel(const int* __restrict__ idx_i, const int* __restrict__ idx_j,
                             const float* __restrict__ cut, const float* __restrict__ dir,
                             const float* __restrict__ rbf, const int* __restrict__ offsets,
                             int* __restrict__ cursor, uint* __restrict__ edata) {
  int e = blockIdx.x * blockDim.x + threadIdx.x;
  if (e >= NE) return;
  int i = idx_i[e];
  int pos = atomicAdd(&cursor[i], 1);
  uint* d = edata + (size_t)(offsets[i] + pos) * 16;
  d[0] = (uint)idx_j[e];
  d[1] = __float_as_uint(cut[e]);
  d[2] = __float_as_uint(dir[e * 3 + 0]);
  d[3] = __float_as_uint(dir[e * 3 + 1]);
  d[4] = __float_as_uint(dir[e * 3 + 2]);
  d[5] = 0u;
  const float* rb = rbf + (size_t)e * NRBF;
#pragma unroll
  for (int r = 0; r < 10; r++) {
    uint lo = (uint)f2bf(rb[2 * r]);
    uint hi = (uint)f2bf(rb[2 * r + 1]);
    d[6 + r] = (hi << 16) | lo;
  }
}

// ---------------- node-centric accumulation: 2 nodes x 128 features ----------------
__global__ __launch_bounds__(256, 4) void node_kernel(
    const uint* __restrict__ edata, const float* __restrict__ Wr,
    const float* __restrict__ br, const ushort* __restrict__ phi_b,
    const float* __restrict__ sf, const float* __restrict__ vf,
    const ushort* __restrict__ vfb, const int* __restrict__ offsets,
    float* __restrict__ out) {
  __shared__ float wr_s[NRBF * PHI_DIM];  // 30720 B
  const int t = threadIdx.x;
  const int f = t & 127;
  const int g = t >> 7;  // node slot 0..1
  for (int i = t; i < NRBF * PHI_DIM; i += 256) wr_s[i] = Wr[i];
  __syncthreads();
  const int n = blockIdx.x * 2 + g;
  const int beg = offsets[n], end = offsets[n + 1];
  const float br0 = br[f], br1 = br[f + 128], br2 = br[f + 256];
  float ss = 0.f, vx = 0.f, vy = 0.f, vz = 0.f;
  for (int p = beg; p < end; p++) {
    const int pu = __builtin_amdgcn_readfirstlane(p);
    const uint4* rec = (const uint4*)(edata + (size_t)pu * 16);
    uint4 q0 = rec[0];
    uint4 q1 = rec[1];
    uint4 q2 = rec[2];
    uint4 q3 = rec[3];
    const int j = (int)q0.x;
    const float c = __uint_as_float(q0.y);
    const float dx = __uint_as_float(q0.z);
    const float dy = __uint_as_float(q0.w);
    const float dz = __uint_as_float(q1.x);
    uint rbp[10] = {q1.z, q1.w, q2.x, q2.y, q2.z, q2.w, q3.x, q3.y, q3.z, q3.w};
    float rv[NRBF];
#pragma unroll
    for (int r = 0; r < 10; r++) {
      rv[2 * r] = __uint_as_float(rbp[r] << 16);
      rv[2 * r + 1] = __uint_as_float(rbp[r] & 0xffff0000u);
    }
    float g0 = br0, g1 = br1, g2 = br2;
#pragma unroll
    for (int r = 0; r < NRBF; r++) {
      float rvv = rv[r];
      g0 += rvv * wr_s[r * PHI_DIM + f];
      g1 += rvv * wr_s[r * PHI_DIM + f + 128];
      g2 += rvv * wr_s[r * PHI_DIM + f + 256];
    }
    g0 *= c; g1 *= c; g2 *= c;
    const ushort* pj = phi_b + (size_t)j * PHI_DIM;
    const float vv = bf2f(pj[f]) * g0;
    const float sv = bf2f(pj[f + 128]) * g1;
    const float vs = bf2f(pj[f + 256]) * g2;
    ss += sv;
    const ushort* vj = vfb + (size_t)j * PHI_DIM;
    vx += bf2f(vj[f]) * vv + vs * dx;
    vy += bf2f(vj[f + 128]) * vv + vs * dy;
    vz += bf2f(vj[f + 256]) * vv + vs * dz;
  }
  const float inv = 1.0f / (float)(end - beg);
  out[(size_t)n * FDIM + f] = sf[(size_t)n * FDIM + f] + ss * inv;
  float* ov = out + (size_t)NN * FDIM + (size_t)n * (FDIM * 3) + f * 3;
  const float* iv = vf + (size_t)n * (FDIM * 3) + f * 3;
  ov[0] = iv[0] + vx * inv;
  ov[1] = iv[1] + vy * inv;
  ov[2] = iv[2] + vz * inv;
}

extern "C" void kernel_launch(void* const* d_in, const int* in_sizes, int n_in,
                              void* d_out, int out_size, void* d_ws, size_t ws_size,
                              hipStream_t stream) {
  const int* idx_i = (const int*)d_in[0];
  const int* idx_j = (const int*)d_in[1];
  const float* rel_dir = (const float*)d_in[2];
  const float* cut = (const float*)d_in[3];
  const float* rbf = (const float*)d_in[4];
  const float* sf = (const float*)d_in[5];
  const float* vf = (const float*)d_in[6];
  const float* W1 = (const float*)d_in[7];
  const float* b1 = (const float*)d_in[8];
  const float* W2 = (const float*)d_in[9];
  const float* b2 = (const float*)d_in[10];
  const float* Wr = (const float*)d_in[11];
  const float* br = (const float*)d_in[12];
  float* out = (float*)d_out;

  char* w = (char*)d_ws;
  int* counts = (int*)w;                      // [0, 40000)
  int* cursor = (int*)(w + 40000);            // [40000, 80000)
  int* offsets = (int*)(w + 80000);           // [80000, 120064) 10001 ints padded
  uint* edata = (uint*)(w + 120064);          // 320000 * 64 B = 20,480,000
  ushort* phi_b = (ushort*)(w + 120064 + 20480000);            // 7,680,000 B
  ushort* vfb = (ushort*)(w + 120064 + 20480000 + 7680000);    // 7,680,000 B

  hipMemsetAsync(w, 0, 80000, stream);  // zero counts + cursor
  hipLaunchKernelGGL(phi_kernel, dim3(NN / 8), dim3(128), 0, stream, sf, W1, b1, W2, b2, phi_b);
  hipLaunchKernelGGL(vfb_kernel, dim3(NN), dim3(128), 0, stream, vf, vfb);
  hipLaunchKernelGGL(count_kernel, dim3((NE + 255) / 256), dim3(256), 0, stream, idx_i, counts);
  hipLaunchKernelGGL(scan_kernel, dim3(1), dim3(1024), 0, stream, counts, offsets);
  hipLaunchKernelGGL(stage_kernel, dim3((NE + 255) / 256), dim3(256), 0, stream, idx_i, idx_j,
                     cut, rel_dir, rbf, offsets, cursor, edata);
  hipLaunchKernelGGL(node_kernel, dim3(NN / 2), dim3(256), 0, stream, edata, Wr, br, phi_b, sf,
                     vf, vfb, offsets, out);
}